// Round 3
// baseline (246.378 us; speedup 1.0000x reference)
//
#include <hip/hip_runtime.h>
#include <math.h>

#define NSAMPLE 32
constexpr int B_ = 2, N_ = 8192, C_ = 64, C1_ = 128, C2_ = 128, CIN_ = 67;
constexpr int KP = 96;            // padded Cin for GEMM1 (3 k-steps of 32)
constexpr int XPAD = 104;         // XT row stride (52 dwords -> 2-way max aliasing)
constexpr int HPAD = 136;         // HT row stride (68 dwords -> 2-way max aliasing)
constexpr float BQ_R2 = 0.15f * 0.15f;
constexpr float EPS_ = 1e-5f;

typedef __attribute__((ext_vector_type(8))) short bf16x8;   // 8 bf16 = 4 VGPR
typedef __attribute__((ext_vector_type(4))) short short4v;
typedef __attribute__((ext_vector_type(4))) float f32x4;

__device__ __forceinline__ short f2bf(float x) {
    union { float f; unsigned u; } v; v.f = x;
    return (short)((v.u + 0x7FFFu + ((v.u >> 16) & 1u)) >> 16);   // RNE
}

// ---- prep: transpose f [B,C,N] fp32 -> fT [B*N][64] bf16; last block: weights
__global__ __launch_bounds__(256) void prep_kernel(
    const float* __restrict__ f, short* __restrict__ fT,
    const float* __restrict__ W1,
    const float* __restrict__ g1, const float* __restrict__ b1,
    const float* __restrict__ m1, const float* __restrict__ v1,
    const float* __restrict__ W2,
    const float* __restrict__ g2, const float* __restrict__ b2,
    const float* __restrict__ m2, const float* __restrict__ v2,
    short* __restrict__ W1p, short* __restrict__ W2p, float* __restrict__ bn)
{
    if (blockIdx.x < (B_ * N_) / 256) {
        int g = blockIdx.x * 256 + threadIdx.x;            // 0..B*N-1
        int b = g >> 13, n = g & (N_ - 1);
        const float* fb = f + (size_t)b * C_ * N_ + n;     // lanes coalesced over n
        short* row = fT + (size_t)g * C_;
        #pragma unroll
        for (int c0 = 0; c0 < C_; c0 += 8) {
            bf16x8 v;
            #pragma unroll
            for (int c = 0; c < 8; ++c) v[c] = f2bf(fb[(size_t)(c0 + c) * N_]);
            *(bf16x8*)&row[c0] = v;                        // 16B store
        }
    } else if (threadIdx.x < 128) {
        int t = threadIdx.x;
        // W1p layout: k 0..2 = dp, 3..7 = 0, 8..71 = f channels, 72..95 = 0
        short* r1 = W1p + t * KP;
        #pragma unroll
        for (int k = 0; k < 3; ++k) r1[k] = f2bf(W1[t * CIN_ + k]);
        #pragma unroll
        for (int k = 3; k < 8; ++k) r1[k] = 0;
        for (int c = 0; c < 64; ++c) r1[8 + c] = f2bf(W1[t * CIN_ + 3 + c]);
        #pragma unroll
        for (int k = 72; k < KP; ++k) r1[k] = 0;
        short* r2 = W2p + t * C1_;
        for (int c = 0; c < C1_; ++c) r2[c] = f2bf(W2[t * C1_ + c]);
        float s1 = g1[t] * rsqrtf(v1[t] + EPS_);
        bn[t] = s1;            bn[128 + t] = b1[t] - m1[t] * s1;
        float s2 = g2[t] * rsqrtf(v2[t] + EPS_);
        bn[256 + t] = s2;      bn[384 + t] = b2[t] - m2[t] * s2;
    }
}

// ---- fused: ball query + gather + GEMM1+BN/ReLU + GEMM2+BN + max ----------
// Block: 256 thr (4 waves), 4 points. Wave w queries point n0+w.
// GEMM phase: wave w owns rows (w&1)*64..+63 x cols (w>>1)*64..+63.
// LDS: XT[128][XPAD] (union'd with) HT[128][HPAD] -- XT dead after GEMM1.
__global__ __launch_bounds__(256) void fused_mfma_kernel(
    const float* __restrict__ p, const short* __restrict__ fT,
    const short* __restrict__ W1p, const short* __restrict__ W2p,
    const float* __restrict__ bn, float* __restrict__ out)
{
    __shared__ short smem[128 * HPAD];   // 34816 B, XT/HT union
    __shared__ float sBN[4][128];
    __shared__ int sidx[4][NSAMPLE];

    int tid = threadIdx.x;
    int bk = blockIdx.x;
    bk = (bk & 7) * 512 + (bk >> 3);     // XCD-contiguous swizzle (4096 = 8*512)
    int b = bk >> 11;
    int n0 = (bk & 2047) * 4;
    int lane = tid & 63, w = tid >> 6;
    int lr = lane & 15, lq = lane >> 4;

    if (tid < 128) {
        sBN[0][tid] = bn[tid];       sBN[1][tid] = bn[128 + tid];
        sBN[2][tid] = bn[256 + tid]; sBN[3][tid] = bn[384 + tid];
    }

    // ---- ball query: wave w handles point n0+w (64 candidates / iter) ----
    const float* pb = p + (size_t)b * N_ * 3;
    {
        int nq = n0 + w;
        float qx = pb[3 * nq], qy = pb[3 * nq + 1], qz = pb[3 * nq + 2];
        int cnt = 0, first = -1;
        for (int j0 = 0; j0 < N_; j0 += 64) {
            int j = j0 + lane;
            float dx = __fadd_rn(pb[3 * j], -qx);
            float dy = __fadd_rn(pb[3 * j + 1], -qy);
            float dz = __fadd_rn(pb[3 * j + 2], -qz);
            float d2 = __fadd_rn(__fadd_rn(__fmul_rn(dx, dx), __fmul_rn(dy, dy)),
                                 __fmul_rn(dz, dz));
            bool hit = d2 < BQ_R2;
            unsigned long long m = __ballot(hit);
            if (hit) {
                int pos = cnt + __popcll(m & ((1ull << lane) - 1ull));
                if (pos < NSAMPLE) sidx[w][pos] = j;
            }
            if (first < 0 && m) first = j0 + (__ffsll((long long)m) - 1);
            cnt += __popcll(m);
            if (cnt >= NSAMPLE) break;   // wave-uniform
        }
        for (int k2 = cnt + lane; k2 < NSAMPLE; k2 += 64) sidx[w][k2] = first;
    }
    __syncthreads();

    // ---- stage XT: 8 threads per column; pads written inline ----
    #pragma unroll
    for (int pass = 0; pass < 4; ++pass) {
        int col = pass * 32 + (tid >> 3);
        int part = tid & 7;
        int pp = col >> 5, k = col & 31;
        int j = sidx[pp][k];
        *(bf16x8*)&smem[col * XPAD + 8 + part * 8] =
            *(const bf16x8*)&fT[((size_t)(b << 13) + j) * C_ + part * 8];
        if (part == 0) {
            int n = n0 + pp;
            bf16x8 v = {0, 0, 0, 0, 0, 0, 0, 0};
            v[0] = f2bf(__fadd_rn(pb[3 * j],     -pb[3 * n]));
            v[1] = f2bf(__fadd_rn(pb[3 * j + 1], -pb[3 * n + 1]));
            v[2] = f2bf(__fadd_rn(pb[3 * j + 2], -pb[3 * n + 2]));
            *(bf16x8*)&smem[col * XPAD] = v;             // k 0..7 (dp + zeros)
        } else if (part <= 3) {
            bf16x8 z = {0, 0, 0, 0, 0, 0, 0, 0};
            *(bf16x8*)&smem[col * XPAD + 72 + (part - 1) * 8] = z;  // k 72..95
        }
    }
    __syncthreads();

    int wr = (w & 1) * 64;   // row (out-channel) base
    int wc = (w >> 1) * 64;  // col (sample) base

    // ---- GEMM1: [128x96] x [96x128] (B from XT) ----
    f32x4 acc[4][4];
    #pragma unroll
    for (int m = 0; m < 4; ++m)
        #pragma unroll
        for (int nt = 0; nt < 4; ++nt) acc[m][nt] = (f32x4){0.f, 0.f, 0.f, 0.f};
    #pragma unroll
    for (int ks = 0; ks < 3; ++ks) {
        bf16x8 a[4];
        #pragma unroll
        for (int m = 0; m < 4; ++m)
            a[m] = *(const bf16x8*)&W1p[(wr + m * 16 + lr) * KP + ks * 32 + lq * 8];
        #pragma unroll
        for (int nt = 0; nt < 4; ++nt) {
            bf16x8 bf = *(const bf16x8*)&smem[(wc + nt * 16 + lr) * XPAD + ks * 32 + lq * 8];
            #pragma unroll
            for (int m = 0; m < 4; ++m)
                acc[m][nt] = __builtin_amdgcn_mfma_f32_16x16x32_bf16(a[m], bf, acc[m][nt], 0, 0, 0);
        }
    }
    __syncthreads();          // all XT reads done before HT overwrites

    // ---- BN1 + ReLU -> HT (bf16, [col][c]) ----
    #pragma unroll
    for (int m = 0; m < 4; ++m) {
        int rb = wr + m * 16 + lq * 4;
        float s0 = sBN[0][rb], s1 = sBN[0][rb + 1], s2 = sBN[0][rb + 2], s3 = sBN[0][rb + 3];
        float h0 = sBN[1][rb], h1 = sBN[1][rb + 1], h2 = sBN[1][rb + 2], h3 = sBN[1][rb + 3];
        #pragma unroll
        for (int nt = 0; nt < 4; ++nt) {
            int col = wc + nt * 16 + lr;
            short4v hv;
            hv[0] = f2bf(fmaxf(fmaf(acc[m][nt][0], s0, h0), 0.f));
            hv[1] = f2bf(fmaxf(fmaf(acc[m][nt][1], s1, h1), 0.f));
            hv[2] = f2bf(fmaxf(fmaf(acc[m][nt][2], s2, h2), 0.f));
            hv[3] = f2bf(fmaxf(fmaf(acc[m][nt][3], s3, h3), 0.f));
            *(short4v*)&smem[col * HPAD + rb] = hv;
        }
    }
    __syncthreads();

    // ---- GEMM2: [128x128] x [128x128] (B from HT) ----
    f32x4 acc2[4][4];
    #pragma unroll
    for (int m = 0; m < 4; ++m)
        #pragma unroll
        for (int nt = 0; nt < 4; ++nt) acc2[m][nt] = (f32x4){0.f, 0.f, 0.f, 0.f};
    #pragma unroll
    for (int ks = 0; ks < 4; ++ks) {
        bf16x8 a[4];
        #pragma unroll
        for (int m = 0; m < 4; ++m)
            a[m] = *(const bf16x8*)&W2p[(wr + m * 16 + lr) * C1_ + ks * 32 + lq * 8];
        #pragma unroll
        for (int nt = 0; nt < 4; ++nt) {
            bf16x8 bf = *(const bf16x8*)&smem[(wc + nt * 16 + lr) * HPAD + ks * 32 + lq * 8];
            #pragma unroll
            for (int m = 0; m < 4; ++m)
                acc2[m][nt] = __builtin_amdgcn_mfma_f32_16x16x32_bf16(a[m], bf, acc2[m][nt], 0, 0, 0);
        }
    }

    // ---- BN2 + max over k + ReLU + store ----
    #pragma unroll
    for (int m = 0; m < 4; ++m) {
        int rb = wr + m * 16 + lq * 4;
        float s0 = sBN[2][rb], s1 = sBN[2][rb + 1], s2 = sBN[2][rb + 2], s3 = sBN[2][rb + 3];
        float h0 = sBN[3][rb], h1 = sBN[3][rb + 1], h2 = sBN[3][rb + 2], h3 = sBN[3][rb + 3];
        #pragma unroll
        for (int lp = 0; lp < 2; ++lp) {       // 2 points per wave
            int n = n0 + (w >> 1) * 2 + lp;
            float v0 = fmaxf(fmaf(acc2[m][2 * lp][0], s0, h0), fmaf(acc2[m][2 * lp + 1][0], s0, h0));
            float v1 = fmaxf(fmaf(acc2[m][2 * lp][1], s1, h1), fmaf(acc2[m][2 * lp + 1][1], s1, h1));
            float v2 = fmaxf(fmaf(acc2[m][2 * lp][2], s2, h2), fmaf(acc2[m][2 * lp + 1][2], s2, h2));
            float v3 = fmaxf(fmaf(acc2[m][2 * lp][3], s3, h3), fmaf(acc2[m][2 * lp + 1][3], s3, h3));
            #pragma unroll
            for (int st = 1; st <= 8; st <<= 1) {
                v0 = fmaxf(v0, __shfl_xor(v0, st, 64));
                v1 = fmaxf(v1, __shfl_xor(v1, st, 64));
                v2 = fmaxf(v2, __shfl_xor(v2, st, 64));
                v3 = fmaxf(v3, __shfl_xor(v3, st, 64));
            }
            if (lr == 0) {
                out[((size_t)(b * C2_ + rb))     * N_ + n] = fmaxf(v0, 0.f);
                out[((size_t)(b * C2_ + rb + 1)) * N_ + n] = fmaxf(v1, 0.f);
                out[((size_t)(b * C2_ + rb + 2)) * N_ + n] = fmaxf(v2, 0.f);
                out[((size_t)(b * C2_ + rb + 3)) * N_ + n] = fmaxf(v3, 0.f);
            }
        }
    }
}

extern "C" void kernel_launch(void* const* d_in, const int* in_sizes, int n_in,
                              void* d_out, int out_size, void* d_ws, size_t ws_size,
                              hipStream_t stream) {
    const float* p   = (const float*)d_in[0];
    const float* f   = (const float*)d_in[1];
    const float* W1  = (const float*)d_in[2];
    const float* g1  = (const float*)d_in[3];
    const float* bb1 = (const float*)d_in[4];
    const float* m1  = (const float*)d_in[5];
    const float* v1  = (const float*)d_in[6];
    const float* W2  = (const float*)d_in[7];
    const float* g2  = (const float*)d_in[8];
    const float* bb2 = (const float*)d_in[9];
    const float* m2  = (const float*)d_in[10];
    const float* v2  = (const float*)d_in[11];
    float* out = (float*)d_out;

    char* ws = (char*)d_ws;
    short* fT  = (short*)ws;                          // 2 MB
    short* W1p = (short*)(ws + (2 << 20));            // 24 KB
    short* W2p = (short*)(ws + (2 << 20) + 0x6000);   // 32 KB
    float* bnv = (float*)(ws + (2 << 20) + 0xE000);   // 2 KB

    prep_kernel<<<(B_ * N_) / 256 + 1, 256, 0, stream>>>(
        f, fT, W1, g1, bb1, m1, v1, W2, g2, bb2, m2, v2, W1p, W2p, bnv);
    fused_mfma_kernel<<<(B_ * N_) / 4, 256, 0, stream>>>(p, fT, W1p, W2p, bnv, out);
}

// Round 4
// 181.315 us; speedup vs baseline: 1.3588x; 1.3588x over previous
//
#include <hip/hip_runtime.h>
#include <math.h>

#define NSAMPLE 32
constexpr int B_ = 2, N_ = 8192, C_ = 64, C1_ = 128, C2_ = 128, CIN_ = 67;
constexpr int KP = 96;            // padded Cin for GEMM1 (3 k-steps of 32)
constexpr int XPAD = 104;         // XT row stride (52 dwords -> 2-way max aliasing)
constexpr int HPAD = 136;         // HT row stride (68 dwords -> 2-way max aliasing)
constexpr float BQ_R2 = 0.15f * 0.15f;
constexpr float EPS_ = 1e-5f;

typedef __attribute__((ext_vector_type(8))) short bf16x8;   // 8 bf16 = 4 VGPR
typedef __attribute__((ext_vector_type(4))) short short4v;
typedef __attribute__((ext_vector_type(4))) float f32x4;

__device__ __forceinline__ short f2bf(float x) {
    union { float f; unsigned u; } v; v.f = x;
    return (short)((v.u + 0x7FFFu + ((v.u >> 16) & 1u)) >> 16);   // RNE
}

// ---- prep: blocks [0,64): transpose f -> fT bf16 [B*N][64]
//      block 64      : weight/BN prep
//      blocks [65, 65+4096): ball query, one wave per point, 256 cand/iter
constexpr int TBLK = (B_ * N_) / 256;        // 64
constexpr int QBLK0 = TBLK + 1;              // 65

__global__ __launch_bounds__(256) void prep_query_kernel(
    const float* __restrict__ p, const float* __restrict__ f,
    short* __restrict__ fT, int* __restrict__ idx,
    const float* __restrict__ W1,
    const float* __restrict__ g1, const float* __restrict__ b1,
    const float* __restrict__ m1, const float* __restrict__ v1,
    const float* __restrict__ W2,
    const float* __restrict__ g2, const float* __restrict__ b2,
    const float* __restrict__ m2, const float* __restrict__ v2,
    short* __restrict__ W1p, short* __restrict__ W2p, float* __restrict__ bn)
{
    int blk = blockIdx.x;
    if (blk < TBLK) {
        // ---------------- transpose f [B,C,N] fp32 -> fT [B*N][64] bf16 ----
        int g = blk * 256 + threadIdx.x;                   // 0..B*N-1
        int b = g >> 13, n = g & (N_ - 1);
        const float* fb = f + (size_t)b * C_ * N_ + n;     // coalesced over n
        short* row = fT + (size_t)g * C_;
        #pragma unroll
        for (int c0 = 0; c0 < C_; c0 += 8) {
            bf16x8 v;
            #pragma unroll
            for (int c = 0; c < 8; ++c) v[c] = f2bf(fb[(size_t)(c0 + c) * N_]);
            *(bf16x8*)&row[c0] = v;                        // 16B store
        }
    } else if (blk == TBLK) {
        // ---------------- weight / BN prep --------------------------------
        if (threadIdx.x >= 128) return;
        int t = threadIdx.x;
        short* r1 = W1p + t * KP;     // k 0..2 dp, 3..7 zero, 8..71 f, 72..95 zero
        #pragma unroll
        for (int k = 0; k < 3; ++k) r1[k] = f2bf(W1[t * CIN_ + k]);
        #pragma unroll
        for (int k = 3; k < 8; ++k) r1[k] = 0;
        for (int c = 0; c < 64; ++c) r1[8 + c] = f2bf(W1[t * CIN_ + 3 + c]);
        #pragma unroll
        for (int k = 72; k < KP; ++k) r1[k] = 0;
        short* r2 = W2p + t * C1_;
        for (int c = 0; c < C1_; ++c) r2[c] = f2bf(W2[t * C1_ + c]);
        float s1 = g1[t] * rsqrtf(v1[t] + EPS_);
        bn[t] = s1;            bn[128 + t] = b1[t] - m1[t] * s1;
        float s2 = g2[t] * rsqrtf(v2[t] + EPS_);
        bn[256 + t] = s2;      bn[384 + t] = b2[t] - m2[t] * s2;
    } else {
        // ---------------- ball query: wave per point, 256 candidates/iter --
        int wid = (blk - QBLK0) * 4 + (threadIdx.x >> 6);   // 0..B*N-1
        int lane = threadIdx.x & 63;
        int b = wid >> 13, n = wid & (N_ - 1);
        const float* pb = p + (size_t)b * N_ * 3;
        float qx = pb[3 * n], qy = pb[3 * n + 1], qz = pb[3 * n + 2];
        int* out = idx + (size_t)wid * NSAMPLE;
        int cnt = 0, first = -1;
        for (int j0 = 0; j0 < N_; j0 += 256) {
            int jb = j0 + 4 * lane;                 // this lane's 4 candidates
            const float* q = pb + 3 * jb;           // 48B, 16B-aligned
            f32x4 u0 = *(const f32x4*)(q);
            f32x4 u1 = *(const f32x4*)(q + 4);
            f32x4 u2 = *(const f32x4*)(q + 8);
            float x0 = u0[0], y0 = u0[1], z0 = u0[2];
            float x1 = u0[3], y1 = u1[0], z1 = u1[1];
            float x2 = u1[2], y2 = u1[3], z2 = u2[0];
            float x3 = u2[1], y3 = u2[2], z3 = u2[3];
            // exact-rn arithmetic (no fma contraction) to match reference classify
            float dx, dy, dz, d2;
            dx = __fadd_rn(x0, -qx); dy = __fadd_rn(y0, -qy); dz = __fadd_rn(z0, -qz);
            d2 = __fadd_rn(__fadd_rn(__fmul_rn(dx, dx), __fmul_rn(dy, dy)), __fmul_rn(dz, dz));
            bool h0 = d2 < BQ_R2;
            dx = __fadd_rn(x1, -qx); dy = __fadd_rn(y1, -qy); dz = __fadd_rn(z1, -qz);
            d2 = __fadd_rn(__fadd_rn(__fmul_rn(dx, dx), __fmul_rn(dy, dy)), __fmul_rn(dz, dz));
            bool h1 = d2 < BQ_R2;
            dx = __fadd_rn(x2, -qx); dy = __fadd_rn(y2, -qy); dz = __fadd_rn(z2, -qz);
            d2 = __fadd_rn(__fadd_rn(__fmul_rn(dx, dx), __fmul_rn(dy, dy)), __fmul_rn(dz, dz));
            bool h2 = d2 < BQ_R2;
            dx = __fadd_rn(x3, -qx); dy = __fadd_rn(y3, -qy); dz = __fadd_rn(z3, -qz);
            d2 = __fadd_rn(__fadd_rn(__fmul_rn(dx, dx), __fmul_rn(dy, dy)), __fmul_rn(dz, dz));
            bool h3 = d2 < BQ_R2;
            unsigned long long m0 = __ballot(h0), m1 = __ballot(h1);
            unsigned long long m2 = __ballot(h2), m3 = __ballot(h3);
            unsigned long long below = (1ull << lane) - 1ull;
            int pos = cnt + __popcll(m0 & below) + __popcll(m1 & below)
                          + __popcll(m2 & below) + __popcll(m3 & below);
            if (h0) { if (pos < NSAMPLE) out[pos] = jb;     ++pos; }
            if (h1) { if (pos < NSAMPLE) out[pos] = jb + 1; ++pos; }
            if (h2) { if (pos < NSAMPLE) out[pos] = jb + 2; ++pos; }
            if (h3) { if (pos < NSAMPLE) out[pos] = jb + 3; ++pos; }
            if (first < 0) {
                int fj = 0x7fffffff;
                if (m0) fj = min(fj, 4 * (__ffsll((long long)m0) - 1));
                if (m1) fj = min(fj, 4 * (__ffsll((long long)m1) - 1) + 1);
                if (m2) fj = min(fj, 4 * (__ffsll((long long)m2) - 1) + 2);
                if (m3) fj = min(fj, 4 * (__ffsll((long long)m3) - 1) + 3);
                if (fj != 0x7fffffff) first = j0 + fj;
            }
            cnt += __popcll(m0) + __popcll(m1) + __popcll(m2) + __popcll(m3);
            if (cnt >= NSAMPLE) break;              // wave-uniform
        }
        for (int k2 = cnt + lane; k2 < NSAMPLE; k2 += 64) out[k2] = first;
    }
}

// ---- fused: gather + GEMM1+BN/ReLU + GEMM2+BN + max -----------------------
// Block: 256 thr (4 waves), 4 points. Wave w owns rows (w&1)*64 x cols (w>>1)*64.
// LDS: XT[128][XPAD] union'd with HT[128][HPAD] (XT dead after GEMM1).
__global__ __launch_bounds__(256) void fused_mfma_kernel(
    const float* __restrict__ p, const int* __restrict__ idx,
    const short* __restrict__ fT, const short* __restrict__ W1p,
    const short* __restrict__ W2p, const float* __restrict__ bn,
    float* __restrict__ out)
{
    __shared__ short smem[128 * HPAD];   // 34816 B, XT/HT union
    __shared__ float sBN[4][128];
    __shared__ int sidx[128];            // 4 points x 32 neighbor indices

    int tid = threadIdx.x;
    int bk = blockIdx.x;
    bk = (bk & 7) * 512 + (bk >> 3);     // XCD-contiguous swizzle (4096 = 8*512)
    int b = bk >> 11;
    int n0 = (bk & 2047) * 4;
    int lane = tid & 63, w = tid >> 6;
    int lr = lane & 15, lq = lane >> 4;

    if (tid < 128) {
        sBN[0][tid] = bn[tid];       sBN[1][tid] = bn[128 + tid];
        sBN[2][tid] = bn[256 + tid]; sBN[3][tid] = bn[384 + tid];
        sidx[tid] = idx[((size_t)((b << 13) + n0)) * NSAMPLE + tid];  // coalesced
    }
    __syncthreads();

    // ---- stage XT: 8 threads per column; pads written inline ----
    const float* pb = p + (size_t)b * N_ * 3;
    #pragma unroll
    for (int pass = 0; pass < 4; ++pass) {
        int col = pass * 32 + (tid >> 3);           // 0..127 == pp*32 + k
        int part = tid & 7;
        int j = sidx[col];
        *(bf16x8*)&smem[col * XPAD + 8 + part * 8] =
            *(const bf16x8*)&fT[((size_t)(b << 13) + j) * C_ + part * 8];
        if (part == 0) {
            int n = n0 + (col >> 5);
            bf16x8 v = {0, 0, 0, 0, 0, 0, 0, 0};
            v[0] = f2bf(__fadd_rn(pb[3 * j],     -pb[3 * n]));
            v[1] = f2bf(__fadd_rn(pb[3 * j + 1], -pb[3 * n + 1]));
            v[2] = f2bf(__fadd_rn(pb[3 * j + 2], -pb[3 * n + 2]));
            *(bf16x8*)&smem[col * XPAD] = v;        // k 0..7 (dp + zeros)
        } else if (part <= 3) {
            bf16x8 z = {0, 0, 0, 0, 0, 0, 0, 0};
            *(bf16x8*)&smem[col * XPAD + 72 + (part - 1) * 8] = z;  // k 72..95
        }
    }
    __syncthreads();

    int wr = (w & 1) * 64;   // row (out-channel) base
    int wc = (w >> 1) * 64;  // col (sample) base

    // ---- GEMM1: [128x96] x [96x128] (B from XT) ----
    f32x4 acc[4][4];
    #pragma unroll
    for (int m = 0; m < 4; ++m)
        #pragma unroll
        for (int nt = 0; nt < 4; ++nt) acc[m][nt] = (f32x4){0.f, 0.f, 0.f, 0.f};
    #pragma unroll
    for (int ks = 0; ks < 3; ++ks) {
        bf16x8 a[4];
        #pragma unroll
        for (int m = 0; m < 4; ++m)
            a[m] = *(const bf16x8*)&W1p[(wr + m * 16 + lr) * KP + ks * 32 + lq * 8];
        #pragma unroll
        for (int nt = 0; nt < 4; ++nt) {
            bf16x8 bf = *(const bf16x8*)&smem[(wc + nt * 16 + lr) * XPAD + ks * 32 + lq * 8];
            #pragma unroll
            for (int m = 0; m < 4; ++m)
                acc[m][nt] = __builtin_amdgcn_mfma_f32_16x16x32_bf16(a[m], bf, acc[m][nt], 0, 0, 0);
        }
    }
    __syncthreads();          // all XT reads done before HT overwrites

    // ---- BN1 + ReLU -> HT (bf16, [col][c]) ----
    #pragma unroll
    for (int m = 0; m < 4; ++m) {
        int rb = wr + m * 16 + lq * 4;
        float s0 = sBN[0][rb], s1 = sBN[0][rb + 1], s2 = sBN[0][rb + 2], s3 = sBN[0][rb + 3];
        float h0 = sBN[1][rb], h1 = sBN[1][rb + 1], h2 = sBN[1][rb + 2], h3 = sBN[1][rb + 3];
        #pragma unroll
        for (int nt = 0; nt < 4; ++nt) {
            int col = wc + nt * 16 + lr;
            short4v hv;
            hv[0] = f2bf(fmaxf(fmaf(acc[m][nt][0], s0, h0), 0.f));
            hv[1] = f2bf(fmaxf(fmaf(acc[m][nt][1], s1, h1), 0.f));
            hv[2] = f2bf(fmaxf(fmaf(acc[m][nt][2], s2, h2), 0.f));
            hv[3] = f2bf(fmaxf(fmaf(acc[m][nt][3], s3, h3), 0.f));
            *(short4v*)&smem[col * HPAD + rb] = hv;
        }
    }
    __syncthreads();

    // ---- GEMM2: [128x128] x [128x128] (B from HT) ----
    f32x4 acc2[4][4];
    #pragma unroll
    for (int m = 0; m < 4; ++m)
        #pragma unroll
        for (int nt = 0; nt < 4; ++nt) acc2[m][nt] = (f32x4){0.f, 0.f, 0.f, 0.f};
    #pragma unroll
    for (int ks = 0; ks < 4; ++ks) {
        bf16x8 a[4];
        #pragma unroll
        for (int m = 0; m < 4; ++m)
            a[m] = *(const bf16x8*)&W2p[(wr + m * 16 + lr) * C1_ + ks * 32 + lq * 8];
        #pragma unroll
        for (int nt = 0; nt < 4; ++nt) {
            bf16x8 bf = *(const bf16x8*)&smem[(wc + nt * 16 + lr) * HPAD + ks * 32 + lq * 8];
            #pragma unroll
            for (int m = 0; m < 4; ++m)
                acc2[m][nt] = __builtin_amdgcn_mfma_f32_16x16x32_bf16(a[m], bf, acc2[m][nt], 0, 0, 0);
        }
    }

    // ---- BN2 + max over k + ReLU + store ----
    #pragma unroll
    for (int m = 0; m < 4; ++m) {
        int rb = wr + m * 16 + lq * 4;
        float s0 = sBN[2][rb], s1 = sBN[2][rb + 1], s2 = sBN[2][rb + 2], s3 = sBN[2][rb + 3];
        float h0 = sBN[3][rb], h1 = sBN[3][rb + 1], h2 = sBN[3][rb + 2], h3 = sBN[3][rb + 3];
        #pragma unroll
        for (int lp = 0; lp < 2; ++lp) {       // 2 points per wave
            int n = n0 + (w >> 1) * 2 + lp;
            float v0 = fmaxf(fmaf(acc2[m][2 * lp][0], s0, h0), fmaf(acc2[m][2 * lp + 1][0], s0, h0));
            float v1 = fmaxf(fmaf(acc2[m][2 * lp][1], s1, h1), fmaf(acc2[m][2 * lp + 1][1], s1, h1));
            float v2 = fmaxf(fmaf(acc2[m][2 * lp][2], s2, h2), fmaf(acc2[m][2 * lp + 1][2], s2, h2));
            float v3 = fmaxf(fmaf(acc2[m][2 * lp][3], s3, h3), fmaf(acc2[m][2 * lp + 1][3], s3, h3));
            #pragma unroll
            for (int st = 1; st <= 8; st <<= 1) {
                v0 = fmaxf(v0, __shfl_xor(v0, st, 64));
                v1 = fmaxf(v1, __shfl_xor(v1, st, 64));
                v2 = fmaxf(v2, __shfl_xor(v2, st, 64));
                v3 = fmaxf(v3, __shfl_xor(v3, st, 64));
            }
            if (lr == 0) {
                out[((size_t)(b * C2_ + rb))     * N_ + n] = fmaxf(v0, 0.f);
                out[((size_t)(b * C2_ + rb + 1)) * N_ + n] = fmaxf(v1, 0.f);
                out[((size_t)(b * C2_ + rb + 2)) * N_ + n] = fmaxf(v2, 0.f);
                out[((size_t)(b * C2_ + rb + 3)) * N_ + n] = fmaxf(v3, 0.f);
            }
        }
    }
}

extern "C" void kernel_launch(void* const* d_in, const int* in_sizes, int n_in,
                              void* d_out, int out_size, void* d_ws, size_t ws_size,
                              hipStream_t stream) {
    const float* p   = (const float*)d_in[0];
    const float* f   = (const float*)d_in[1];
    const float* W1  = (const float*)d_in[2];
    const float* g1  = (const float*)d_in[3];
    const float* bb1 = (const float*)d_in[4];
    const float* m1  = (const float*)d_in[5];
    const float* v1  = (const float*)d_in[6];
    const float* W2  = (const float*)d_in[7];
    const float* g2  = (const float*)d_in[8];
    const float* bb2 = (const float*)d_in[9];
    const float* m2  = (const float*)d_in[10];
    const float* v2  = (const float*)d_in[11];
    float* out = (float*)d_out;

    char* ws = (char*)d_ws;
    int*   idxbuf = (int*)ws;                         // 2 MB
    short* fT  = (short*)(ws + (2 << 20));            // 2 MB
    short* W1p = (short*)(ws + (4 << 20));            // 24 KB
    short* W2p = (short*)(ws + (4 << 20) + 0x6000);   // 32 KB
    float* bnv = (float*)(ws + (4 << 20) + 0xE000);   // 2 KB

    prep_query_kernel<<<QBLK0 + (B_ * N_) / 4, 256, 0, stream>>>(
        p, f, fT, idxbuf, W1, g1, bb1, m1, v1, W2, g2, bb2, m2, v2,
        W1p, W2p, bnv);
    fused_mfma_kernel<<<(B_ * N_) / 4, 256, 0, stream>>>(
        p, idxbuf, fT, W1p, W2p, bnv, out);
}